// Round 1
// baseline (220.475 us; speedup 1.0000x reference)
//
#include <hip/hip_runtime.h>

#define SEQ 2048
#define BSZ 2
#define NHEAD 16
#define HDIM 64
#define QBLK 64
#define KVBLK 64
#define LSTR 88   // LDS row stride in bf16 elems (176 B: 16B-aligned, <=2-way conflicts)
#define ROWSTRIDE (BSZ * NHEAD * HDIM)  // 2048 floats between seq positions

typedef __bf16 bf16x8 __attribute__((ext_vector_type(8)));
typedef float f32x4 __attribute__((ext_vector_type(4)));

// XOR swizzle for the transposed tiles (Vt, Zt): spreads the scalar
// transpose-writes across banks; reads use the same involution.
__device__ __forceinline__ int vswz(int row, int col) {
  return row * LSTR + (col ^ (((row >> 2) & 7) << 3));
}

__global__ __launch_bounds__(256)
void ntk_attn(const float* __restrict__ Qg, const float* __restrict__ Kg,
              const float* __restrict__ Vg, const float* __restrict__ PKg,
              const float* __restrict__ PKVg, float* __restrict__ Og) {
  __shared__ __bf16 Ks[KVBLK * LSTR];       // K tile, row-major [kv][d]
  __shared__ __bf16 Vts[HDIM * LSTR];       // V tile transposed [d][kv], swizzled
  __shared__ __bf16 Zts[HDIM * LSTR];       // Z transposed [dout][din], swizzled
  __shared__ __bf16 Ps[4][16 * LSTR];       // per-wave P tile [qrow][kv]
  __shared__ float kks[HDIM];
  __shared__ float red[4][16];

  const int tid = threadIdx.x;
  const int w = tid >> 6;
  const int l = tid & 63;
  const int lr = l & 15;   // lane row-id within 16
  const int lg = l >> 4;   // lane group 0..3
  const int bh = blockIdx.y;              // b*NHEAD + h
  const int h = bh & (NHEAD - 1);
  const int q0 = blockIdx.x * QBLK;
  const int headoff = bh * HDIM;

  // ---- Q fragments + phi(Q) fragments (A-layout: row=lr, k=8*lg+i) ----
  bf16x8 aq[2], pq[2];
  {
    const int qr = q0 + w * 16 + lr;
    const float* qp = Qg + (size_t)qr * ROWSTRIDE + headoff + lg * 8;
#pragma unroll
    for (int c = 0; c < 2; ++c) {
      const float4 x0 = *(const float4*)(qp + 32 * c);
      const float4 x1 = *(const float4*)(qp + 32 * c + 4);
      const float f[8] = {x0.x, x0.y, x0.z, x0.w, x1.x, x1.y, x1.z, x1.w};
#pragma unroll
      for (int i = 0; i < 8; ++i) {
        aq[c][i] = (__bf16)f[i];
        const float xs = f[i] * 0.3535533905932738f;  // x / d^0.25
        pq[c][i] = (__bf16)(xs > 0.f ? xs + 1.f : __expf(xs));  // elu(x)+1
      }
    }
  }

  // ---- stage Zt (transposed, swizzled) and |kk| ----
  {
#pragma unroll
    for (int it = 0; it < 4; ++it) {
      const int din = (tid >> 4) + 16 * it;
      const int c4 = (tid & 15) * 4;
      const float4 z = *(const float4*)(PKVg + (size_t)h * HDIM * HDIM +
                                        (size_t)din * HDIM + c4);
      Zts[vswz(c4 + 0, din)] = (__bf16)z.x;
      Zts[vswz(c4 + 1, din)] = (__bf16)z.y;
      Zts[vswz(c4 + 2, din)] = (__bf16)z.z;
      Zts[vswz(c4 + 3, din)] = (__bf16)z.w;
    }
    if (tid < HDIM) kks[tid] = fabsf(PKg[h * HDIM + tid]);
  }

  const f32x4 z4 = {0.f, 0.f, 0.f, 0.f};
  f32x4 oacc[4] = {z4, z4, z4, z4};
  float m[4] = {-1e30f, -1e30f, -1e30f, -1e30f};
  float lsum[4] = {0.f, 0.f, 0.f, 0.f};
  const int qmax = q0 + QBLK - 1;
  const int qrb = q0 + w * 16 + lg * 4;  // absolute q row for D-layout reg r

  for (int kb = 0; kb < SEQ / KVBLK; ++kb) {
    const int kv0 = kb * KVBLK;
    const bool causal = (kv0 <= qmax);  // block-uniform

    // ---- stage K (row-major) and V (transposed, swizzled) ----
#pragma unroll
    for (int it = 0; it < 4; ++it) {
      const int r = (tid >> 4) + 16 * it;
      const int c4 = (tid & 15) * 4;
      const size_t gaddr = (size_t)(kv0 + r) * ROWSTRIDE + headoff + c4;
      const float4 k4 = *(const float4*)(Kg + gaddr);
      __bf16* kd = &Ks[r * LSTR + c4];
      kd[0] = (__bf16)k4.x; kd[1] = (__bf16)k4.y;
      kd[2] = (__bf16)k4.z; kd[3] = (__bf16)k4.w;
      if (causal) {
        const float4 v4 = *(const float4*)(Vg + gaddr);
        Vts[vswz(c4 + 0, r)] = (__bf16)v4.x;
        Vts[vswz(c4 + 1, r)] = (__bf16)v4.y;
        Vts[vswz(c4 + 2, r)] = (__bf16)v4.z;
        Vts[vswz(c4 + 3, r)] = (__bf16)v4.w;
      }
    }
    __syncthreads();

    // ---- S = Q K^T / sqrt(d) ----
    float sv[4][4];
#pragma unroll
    for (int nj = 0; nj < 4; ++nj) {
      f32x4 acc = z4;
#pragma unroll
      for (int c = 0; c < 2; ++c) {
        const bf16x8 bk = *(const bf16x8*)&Ks[(nj * 16 + lr) * LSTR + 32 * c + lg * 8];
        acc = __builtin_amdgcn_mfma_f32_16x16x32_bf16(aq[c], bk, acc, 0, 0, 0);
      }
#pragma unroll
      for (int r = 0; r < 4; ++r) sv[nj][r] = acc[r] * 0.125f;
    }

    // ---- running UNMASKED row max + rescale of running state ----
#pragma unroll
    for (int r = 0; r < 4; ++r) {
      float mx = fmaxf(fmaxf(sv[0][r], sv[1][r]), fmaxf(sv[2][r], sv[3][r]));
      mx = fmaxf(mx, __shfl_xor(mx, 1));
      mx = fmaxf(mx, __shfl_xor(mx, 2));
      mx = fmaxf(mx, __shfl_xor(mx, 4));
      mx = fmaxf(mx, __shfl_xor(mx, 8));
      const float mn = fmaxf(m[r], mx);
      const float corr = __expf(m[r] - mn);
      m[r] = mn;
      lsum[r] *= corr;
      oacc[0][r] *= corr; oacc[1][r] *= corr;
      oacc[2][r] *= corr; oacc[3][r] *= corr;
    }

    if (causal) {
      // ---- P = exp(S-m) * causal; stash to per-wave LDS for transpose ----
#pragma unroll
      for (int nj = 0; nj < 4; ++nj) {
        const int col = kv0 + nj * 16 + lr;
#pragma unroll
        for (int r = 0; r < 4; ++r) {
          const float p = (col <= qrb + r) ? __expf(sv[nj][r] - m[r]) : 0.f;
          lsum[r] += p;  // lane-partial; reduced at epilogue
          Ps[w][(lg * 4 + r) * LSTR + nj * 16 + lr] = (__bf16)p;
        }
      }
      // wave-local LDS write->read hazard: drain, and pin ordering
      asm volatile("s_waitcnt lgkmcnt(0)" ::: "memory");
      __builtin_amdgcn_sched_barrier(0);

      // ---- O += P V ----
#pragma unroll
      for (int c = 0; c < 2; ++c) {
        const bf16x8 ap = *(const bf16x8*)&Ps[w][lr * LSTR + 32 * c + lg * 8];
#pragma unroll
        for (int dj = 0; dj < 4; ++dj) {
          const bf16x8 bv = *(const bf16x8*)&Vts[vswz(dj * 16 + lr, 32 * c + lg * 8)];
          oacc[dj] = __builtin_amdgcn_mfma_f32_16x16x32_bf16(ap, bv, oacc[dj], 0, 0, 0);
        }
      }
    }
    __syncthreads();
  }

  // ---- epilogue: phi_q @ Z (MFMA) and phi_q . kk ----
  f32x4 zacc[4] = {z4, z4, z4, z4};
#pragma unroll
  for (int c = 0; c < 2; ++c) {
#pragma unroll
    for (int dj = 0; dj < 4; ++dj) {
      const bf16x8 bz = *(const bf16x8*)&Zts[vswz(dj * 16 + lr, 32 * c + lg * 8)];
      zacc[dj] = __builtin_amdgcn_mfma_f32_16x16x32_bf16(pq[c], bz, zacc[dj], 0, 0, 0);
    }
  }
  float pkk = 0.f;
#pragma unroll
  for (int c = 0; c < 2; ++c)
#pragma unroll
    for (int i = 0; i < 8; ++i)
      pkk += (float)pq[c][i] * kks[32 * c + lg * 8 + i];
  pkk += __shfl_xor(pkk, 16);
  pkk += __shfl_xor(pkk, 32);
  if (l < 16) red[w][l] = pkk;  // pkk now valid for row lr; rebroadcast via LDS
  __syncthreads();

#pragma unroll
  for (int r = 0; r < 4; ++r) {
    float s = lsum[r];
    s += __shfl_xor(s, 1); s += __shfl_xor(s, 2);
    s += __shfl_xor(s, 4); s += __shfl_xor(s, 8);
    const float pkr = red[w][lg * 4 + r];
    const float iem = __expf(-m[r]);  // 1/exp(max_A)
    const float rd = 1.f / (s + pkr * iem);
    const int qr = qrb + r;
    float* op = Og + (size_t)qr * ROWSTRIDE + headoff;
#pragma unroll
    for (int dj = 0; dj < 4; ++dj)
      op[dj * 16 + lr] = (oacc[dj][r] + zacc[dj][r] * iem) * rd;
  }
}

extern "C" void kernel_launch(void* const* d_in, const int* in_sizes, int n_in,
                              void* d_out, int out_size, void* d_ws, size_t ws_size,
                              hipStream_t stream) {
  const float* Qg  = (const float*)d_in[0];
  const float* Kg  = (const float*)d_in[1];
  const float* Vg  = (const float*)d_in[2];
  // d_in[3] = attention_mask (unused by the reference forward)
  const float* PKg  = (const float*)d_in[4];
  const float* PKVg = (const float*)d_in[5];
  float* Og = (float*)d_out;
  dim3 grid(SEQ / QBLK, BSZ * NHEAD);
  ntk_attn<<<grid, dim3(256), 0, stream>>>(Qg, Kg, Vg, PKg, PKVg, Og);
}

// Round 2
// 147.847 us; speedup vs baseline: 1.4912x; 1.4912x over previous
//
#include <hip/hip_runtime.h>

#define SEQ 2048
#define BSZ 2
#define NHEAD 16
#define HDIM 64
#define QBLK 64
#define KVBLK 64
#define NKV (SEQ / KVBLK)
#define LSTR 88   // LDS row stride in bf16 elems (176 B)
#define ROWSTRIDE (BSZ * NHEAD * HDIM)

typedef __bf16 bf16x8 __attribute__((ext_vector_type(8)));
typedef __bf16 bf16x4 __attribute__((ext_vector_type(4)));
typedef float f32x4 __attribute__((ext_vector_type(4)));

// XOR swizzle for the transposed tiles (Vt, Zt).
__device__ __forceinline__ int vswz(int row, int col) {
  return row * LSTR + (col ^ (((row >> 2) & 7) << 3));
}

__global__ __launch_bounds__(256)
void ntk_attn(const float* __restrict__ Qg, const float* __restrict__ Kg,
              const float* __restrict__ Vg, const float* __restrict__ PKg,
              const float* __restrict__ PKVg, float* __restrict__ Og) {
  __shared__ __bf16 Ks[KVBLK * LSTR];       // K tile, row-major [kv][d]
  __shared__ __bf16 Vts[HDIM * LSTR];       // V tile transposed [d][kv], swizzled
  __shared__ __bf16 Zts[HDIM * LSTR];       // Z transposed [dout][din], swizzled
  __shared__ __bf16 Ps[4][16 * LSTR];       // per-wave P tile [qrow][kv]
  __shared__ float kks[HDIM];
  __shared__ float red[4][16];

  const int tid = threadIdx.x;
  const int w = tid >> 6;
  const int l = tid & 63;
  const int lr = l & 15;
  const int lg = l >> 4;
  const int bh = blockIdx.y;
  const int h = bh & (NHEAD - 1);
  const int bx = blockIdx.x;
  const int q0 = bx * QBLK;
  const int headoff = bh * HDIM;

  // ---- Q fragments (pre-scaled by 1/sqrt(d), exact pow2) + phi(Q) ----
  bf16x8 aq[2], pq[2];
  {
    const int qr = q0 + w * 16 + lr;
    const float* qp = Qg + (size_t)qr * ROWSTRIDE + headoff + lg * 8;
#pragma unroll
    for (int c = 0; c < 2; ++c) {
      const float4 x0 = *(const float4*)(qp + 32 * c);
      const float4 x1 = *(const float4*)(qp + 32 * c + 4);
      const float f[8] = {x0.x, x0.y, x0.z, x0.w, x1.x, x1.y, x1.z, x1.w};
#pragma unroll
      for (int i = 0; i < 8; ++i) {
        aq[c][i] = (__bf16)(f[i] * 0.125f);
        const float xs = f[i] * 0.3535533905932738f;
        pq[c][i] = (__bf16)(xs > 0.f ? xs + 1.f : __expf(xs));
      }
    }
  }

  // ---- stage Zt (transposed, swizzled) and |kk| ----
  {
#pragma unroll
    for (int it = 0; it < 4; ++it) {
      const int din = (tid >> 4) + 16 * it;
      const int c4 = (tid & 15) * 4;
      const float4 z = *(const float4*)(PKVg + (size_t)h * HDIM * HDIM +
                                        (size_t)din * HDIM + c4);
      Zts[vswz(c4 + 0, din)] = (__bf16)z.x;
      Zts[vswz(c4 + 1, din)] = (__bf16)z.y;
      Zts[vswz(c4 + 2, din)] = (__bf16)z.z;
      Zts[vswz(c4 + 3, din)] = (__bf16)z.w;
    }
    if (tid < HDIM) kks[tid] = fabsf(PKg[h * HDIM + tid]);
  }

  const f32x4 z4 = {0.f, 0.f, 0.f, 0.f};
  f32x4 oacc[4] = {z4, z4, z4, z4};
  float m[4] = {-1e30f, -1e30f, -1e30f, -1e30f};
  float lsum[4] = {0.f, 0.f, 0.f, 0.f};
  float mxl[4] = {-1e30f, -1e30f, -1e30f, -1e30f};  // phase-2 lane-local max
  const int qrb = q0 + w * 16 + lg * 4;

  // ---- register-staged prefetch helpers ----
  const int stg_r = tid >> 4;            // 0..15
  const int stg_c4 = (tid & 15) * 4;     // 0..60
  float4 kreg[4], vreg[4];

  auto issue_k = [&](int kb) {
#pragma unroll
    for (int it = 0; it < 4; ++it)
      kreg[it] = *(const float4*)(Kg + (size_t)(kb * KVBLK + stg_r + 16 * it) * ROWSTRIDE +
                                  headoff + stg_c4);
  };
  auto issue_v = [&](int kb) {
#pragma unroll
    for (int it = 0; it < 4; ++it)
      vreg[it] = *(const float4*)(Vg + (size_t)(kb * KVBLK + stg_r + 16 * it) * ROWSTRIDE +
                                  headoff + stg_c4);
  };
  auto write_k = [&]() {
#pragma unroll
    for (int it = 0; it < 4; ++it) {
      const int r = stg_r + 16 * it;
      bf16x4 p = {(__bf16)kreg[it].x, (__bf16)kreg[it].y,
                  (__bf16)kreg[it].z, (__bf16)kreg[it].w};
      *(bf16x4*)&Ks[r * LSTR + stg_c4] = p;  // 8B-aligned packed write
    }
  };
  auto write_v = [&]() {
#pragma unroll
    for (int it = 0; it < 4; ++it) {
      const int r = stg_r + 16 * it;
      Vts[vswz(stg_c4 + 0, r)] = (__bf16)vreg[it].x;
      Vts[vswz(stg_c4 + 1, r)] = (__bf16)vreg[it].y;
      Vts[vswz(stg_c4 + 2, r)] = (__bf16)vreg[it].z;
      Vts[vswz(stg_c4 + 3, r)] = (__bf16)vreg[it].w;
    }
  };
  // after compute(kb): write tile kb+1 (already in regs), issue tile kb+2
  auto stage_tail = [&](int kb) {
    const int nxt = kb + 1;
    if (nxt < NKV) {
      write_k();
      if (nxt <= bx) write_v();
      const int n2 = kb + 2;
      if (n2 < NKV) {
        issue_k(n2);
        if (n2 <= bx) issue_v(n2);
      }
      __syncthreads();
    }
  };

  // ---- prologue: tile 0 into LDS, tile 1 in flight ----
  issue_k(0); issue_v(0);
  write_k(); write_v();
  issue_k(1);
  if (1 <= bx) issue_v(1);
  __syncthreads();

  // ==== phase 1: causal tiles (kb = 0..bx) ====
  for (int kb = 0; kb <= bx; ++kb) {
    const int kv0 = kb * KVBLK;

    float sv[4][4];
    __builtin_amdgcn_s_setprio(1);
#pragma unroll
    for (int nj = 0; nj < 4; ++nj) {
      f32x4 acc = z4;
#pragma unroll
      for (int c = 0; c < 2; ++c) {
        const bf16x8 bk = *(const bf16x8*)&Ks[(nj * 16 + lr) * LSTR + 32 * c + lg * 8];
        acc = __builtin_amdgcn_mfma_f32_16x16x32_bf16(aq[c], bk, acc, 0, 0, 0);
      }
#pragma unroll
      for (int r = 0; r < 4; ++r) sv[nj][r] = acc[r];
    }
    __builtin_amdgcn_s_setprio(0);

    // online running max (unmasked) + rescale
#pragma unroll
    for (int r = 0; r < 4; ++r) {
      float mx = fmaxf(fmaxf(sv[0][r], sv[1][r]), fmaxf(sv[2][r], sv[3][r]));
      mx = fmaxf(mx, __shfl_xor(mx, 1));
      mx = fmaxf(mx, __shfl_xor(mx, 2));
      mx = fmaxf(mx, __shfl_xor(mx, 4));
      mx = fmaxf(mx, __shfl_xor(mx, 8));
      const float mn = fmaxf(m[r], mx);
      const float corr = __expf(m[r] - mn);
      m[r] = mn;
      lsum[r] *= corr;
      oacc[0][r] *= corr; oacc[1][r] *= corr;
      oacc[2][r] *= corr; oacc[3][r] *= corr;
    }

    // P = exp(S-m) * causal -> per-wave LDS transpose
#pragma unroll
    for (int nj = 0; nj < 4; ++nj) {
      const int col = kv0 + nj * 16 + lr;
#pragma unroll
      for (int r = 0; r < 4; ++r) {
        const float p = (col <= qrb + r) ? __expf(sv[nj][r] - m[r]) : 0.f;
        lsum[r] += p;
        Ps[w][(lg * 4 + r) * LSTR + nj * 16 + lr] = (__bf16)p;
      }
    }
    asm volatile("s_waitcnt lgkmcnt(0)" ::: "memory");
    __builtin_amdgcn_sched_barrier(0);

    // O += P V
    __builtin_amdgcn_s_setprio(1);
#pragma unroll
    for (int c = 0; c < 2; ++c) {
      const bf16x8 ap = *(const bf16x8*)&Ps[w][lr * LSTR + 32 * c + lg * 8];
#pragma unroll
      for (int dj = 0; dj < 4; ++dj) {
        const bf16x8 bv = *(const bf16x8*)&Vts[vswz(dj * 16 + lr, 32 * c + lg * 8)];
        oacc[dj] = __builtin_amdgcn_mfma_f32_16x16x32_bf16(ap, bv, oacc[dj], 0, 0, 0);
      }
    }
    __builtin_amdgcn_s_setprio(0);

    __syncthreads();
    stage_tail(kb);
  }

  // ==== phase 2: max-only tiles (kb = bx+1..NKV-1), lane-local max ====
  for (int kb = bx + 1; kb < NKV; ++kb) {
    __builtin_amdgcn_s_setprio(1);
#pragma unroll
    for (int nj = 0; nj < 4; ++nj) {
      f32x4 acc = z4;
#pragma unroll
      for (int c = 0; c < 2; ++c) {
        const bf16x8 bk = *(const bf16x8*)&Ks[(nj * 16 + lr) * LSTR + 32 * c + lg * 8];
        acc = __builtin_amdgcn_mfma_f32_16x16x32_bf16(aq[c], bk, acc, 0, 0, 0);
      }
#pragma unroll
      for (int r = 0; r < 4; ++r) mxl[r] = fmaxf(mxl[r], acc[r]);
    }
    __builtin_amdgcn_s_setprio(0);
    __syncthreads();
    stage_tail(kb);
  }

  // finalize: fold phase-2 max into running state (one rescale total)
#pragma unroll
  for (int r = 0; r < 4; ++r) {
    float mx = mxl[r];
    mx = fmaxf(mx, __shfl_xor(mx, 1));
    mx = fmaxf(mx, __shfl_xor(mx, 2));
    mx = fmaxf(mx, __shfl_xor(mx, 4));
    mx = fmaxf(mx, __shfl_xor(mx, 8));
    const float mn = fmaxf(m[r], mx);
    const float corr = __expf(m[r] - mn);
    m[r] = mn;
    lsum[r] *= corr;
    oacc[0][r] *= corr; oacc[1][r] *= corr;
    oacc[2][r] *= corr; oacc[3][r] *= corr;
  }

  // ---- epilogue: phi_q @ Z (MFMA) and phi_q . kk ----
  f32x4 zacc[4] = {z4, z4, z4, z4};
#pragma unroll
  for (int c = 0; c < 2; ++c) {
#pragma unroll
    for (int dj = 0; dj < 4; ++dj) {
      const bf16x8 bz = *(const bf16x8*)&Zts[vswz(dj * 16 + lr, 32 * c + lg * 8)];
      zacc[dj] = __builtin_amdgcn_mfma_f32_16x16x32_bf16(pq[c], bz, zacc[dj], 0, 0, 0);
    }
  }
  float pkk = 0.f;
#pragma unroll
  for (int c = 0; c < 2; ++c)
#pragma unroll
    for (int i = 0; i < 8; ++i)
      pkk += (float)pq[c][i] * kks[32 * c + lg * 8 + i];
  pkk += __shfl_xor(pkk, 16);
  pkk += __shfl_xor(pkk, 32);
  if (l < 16) red[w][l] = pkk;
  __syncthreads();

#pragma unroll
  for (int r = 0; r < 4; ++r) {
    float s = lsum[r];
    s += __shfl_xor(s, 1); s += __shfl_xor(s, 2);
    s += __shfl_xor(s, 4); s += __shfl_xor(s, 8);
    const float pkr = red[w][lg * 4 + r];
    const float iem = __expf(-m[r]);
    const float rd = 1.f / (s + pkr * iem);
    const int qr = qrb + r;
    float* op = Og + (size_t)qr * ROWSTRIDE + headoff;
#pragma unroll
    for (int dj = 0; dj < 4; ++dj)
      op[dj * 16 + lr] = (oacc[dj][r] + zacc[dj][r] * iem) * rd;
  }
}

extern "C" void kernel_launch(void* const* d_in, const int* in_sizes, int n_in,
                              void* d_out, int out_size, void* d_ws, size_t ws_size,
                              hipStream_t stream) {
  const float* Qg  = (const float*)d_in[0];
  const float* Kg  = (const float*)d_in[1];
  const float* Vg  = (const float*)d_in[2];
  const float* PKg  = (const float*)d_in[4];
  const float* PKVg = (const float*)d_in[5];
  float* Og = (float*)d_out;
  dim3 grid(SEQ / QBLK, BSZ * NHEAD);
  ntk_attn<<<grid, dim3(256), 0, stream>>>(Qg, Kg, Vg, PKg, PKVg, Og);
}